// Round 6
// baseline (2091.254 us; speedup 1.0000x reference)
//
#include <hip/hip_runtime.h>
#include <hip/hip_bf16.h>
#include <math.h>

#define N_TOK 16384
#define DIM   512
#define FDIM  2048
#define NEXP  8
#define TOPK  2
#define PAIRS (N_TOK*TOPK)             // 32768
#define MAX_TILES (PAIRS/128 + NEXP)   // 264

typedef __hip_bfloat16 bf16;
typedef __attribute__((ext_vector_type(8))) short bf16x8;
typedef __attribute__((ext_vector_type(4))) float f32x4;
typedef __attribute__((ext_vector_type(8))) short s16x8;

__device__ __forceinline__ short f2bf(float f){
  union { float f; unsigned u; } v; v.f = f;
  unsigned r = v.u + 0x7fffu + ((v.u >> 16) & 1u);
  return (short)(r >> 16);
}
__device__ __forceinline__ float bf2f(short s){
  union { unsigned u; float f; } v; v.u = ((unsigned)(unsigned short)s) << 16;
  return v.f;
}
// async global->LDS, 16B per lane. LDS dest = wave-uniform base + lane*16.
__device__ __forceinline__ void g2l16(const void* g, void* l){
  __builtin_amdgcn_global_load_lds(
      (const __attribute__((address_space(1))) unsigned int*)g,
      (__attribute__((address_space(3))) unsigned int*)l, 16, 0, 0);
}

// ---------------- gating: fp32 logits, top-2, softmax. NO global atomics ----------------
__global__ __launch_bounds__(512) void k_gate(const float* __restrict__ x,
    const float* __restrict__ gw, int* __restrict__ tidx, float* __restrict__ tw){
  __shared__ float gwT[NEXP][DIM];     // 16 KB, transposed: gwT[e][d]
  int tid = threadIdx.x;
  #pragma unroll
  for(int i=0;i<8;i++){
    int idx = tid + 512*i;             // 4096 floats
    gwT[idx&7][idx>>3] = gw[idx];
  }
  __syncthreads();
  int lane = tid & 63, wid = tid >> 6;
  int t = blockIdx.x*8 + wid;
  const float* xr = x + (size_t)t*DIM;
  float acc[NEXP];
  #pragma unroll
  for(int e=0;e<NEXP;e++) acc[e]=0.f;
  #pragma unroll
  for(int c=0;c<8;c++){
    float xv = xr[c*64 + lane];        // coalesced 256B per wave-load
    #pragma unroll
    for(int e=0;e<NEXP;e++) acc[e] += xv * gwT[e][c*64+lane];  // stride-1: conflict-free
  }
  #pragma unroll
  for(int off=32; off; off>>=1){
    #pragma unroll
    for(int e=0;e<NEXP;e++) acc[e] += __shfl_xor(acc[e], off);
  }
  if(lane==0){
    int e0=0; float v0=acc[0];
    #pragma unroll
    for(int e=1;e<NEXP;e++) if(acc[e]>v0){v0=acc[e]; e0=e;}
    int e1=-1; float v1=-1e30f;
    #pragma unroll
    for(int e=0;e<NEXP;e++) if(e!=e0 && acc[e]>v1){v1=acc[e]; e1=e;}
    float z = expf(v1-v0);
    float w0 = 1.f/(1.f+z);
    tidx[t*2]=e0; tidx[t*2+1]=e1;
    tw[t*2]=w0; tw[t*2+1]=1.f-w0;
  }
}

// ---------------- histogram: 8 global atomics per block ----------------
__global__ __launch_bounds__(256) void k_count(const int* __restrict__ tidx,
                                               int* __restrict__ counts){
  __shared__ int h[NEXP];
  if(threadIdx.x<NEXP) h[threadIdx.x]=0;
  __syncthreads();
  int i0 = blockIdx.x*1024 + threadIdx.x;
  #pragma unroll
  for(int k=0;k<4;k++) atomicAdd(&h[tidx[i0 + 256*k]], 1);
  __syncthreads();
  if(threadIdx.x<NEXP) atomicAdd(&counts[threadIdx.x], h[threadIdx.x]);
}

// ---------------- routing tables: dense offsets, ragged tiles ----------------
__global__ void k_route(const int* __restrict__ counts, int* __restrict__ offsets,
    int* __restrict__ ntiles, int* __restrict__ te, int* __restrict__ tb,
    int* __restrict__ ts){
  if(threadIdx.x==0){
    int off=0, nt=0;
    for(int e=0;e<NEXP;e++){
      offsets[e]=off;
      int c=counts[e];
      int tiles=(c+127)>>7;
      for(int i=0;i<tiles;i++){ te[nt]=e; tb[nt]=off+(i<<7); ts[nt]=off+c; nt++; }
      off += c;
    }
    *ntiles=nt;
  }
}

// ---------------- scatter: block-level reservation, dense positions ----------------
__global__ __launch_bounds__(256) void k_scatter(const int* __restrict__ tidx,
    const int* __restrict__ offsets, int* __restrict__ fill,
    int* __restrict__ token_list, int* __restrict__ posmap){
  __shared__ int lcnt[NEXP], lbase[NEXP];
  if(threadIdx.x<NEXP) lcnt[threadIdx.x]=0;
  __syncthreads();
  int i = blockIdx.x*256 + threadIdx.x;
  int e = tidx[i];
  int rank = atomicAdd(&lcnt[e], 1);          // LDS atomic: cheap
  __syncthreads();
  if(threadIdx.x<NEXP) lbase[threadIdx.x] = atomicAdd(&fill[threadIdx.x], lcnt[threadIdx.x]);
  __syncthreads();
  int pos = offsets[e] + lbase[e] + rank;
  token_list[pos] = i>>1;
  posmap[i] = pos;
}

// ---------------- fp32 -> bf16 cast (x) ----------------
__global__ __launch_bounds__(256) void k_cast(const float* __restrict__ x,
                                              bf16* __restrict__ xb){
  int i = blockIdx.x*256 + threadIdx.x;
  const float* p = x + (size_t)i*8;
  f32x4 a = *(const f32x4*)p;
  f32x4 b = *(const f32x4*)(p+4);
  s16x8 r;
  r[0]=f2bf(a[0]); r[1]=f2bf(a[1]); r[2]=f2bf(a[2]); r[3]=f2bf(a[3]);
  r[4]=f2bf(b[0]); r[5]=f2bf(b[1]); r[6]=f2bf(b[2]); r[7]=f2bf(b[3]);
  *(s16x8*)((short*)xb + (size_t)i*8) = r;
}

// ---------------- transpose+cast: src [R][C] f32 -> dst [C][R] bf16 ----------------
__global__ __launch_bounds__(256) void k_transpose(const float* __restrict__ src,
    bf16* __restrict__ dst, int R, int C){
  __shared__ float tile[32][33];
  const float* s = src + (size_t)blockIdx.z*R*C;
  short* d = (short*)dst + (size_t)blockIdx.z*R*C;
  int c0 = blockIdx.x*32, r0 = blockIdx.y*32;
  int tx = threadIdx.x & 31, ty = threadIdx.x >> 5;
  #pragma unroll
  for(int i=0;i<4;i++) tile[ty+8*i][tx] = s[(size_t)(r0+ty+8*i)*C + c0+tx];
  __syncthreads();
  #pragma unroll
  for(int i=0;i<4;i++) d[(size_t)(c0+ty+8*i)*R + r0+tx] = f2bf(tile[tx][ty+8*i]);
}

// ---------------- GEMM A: H[pos] = silu(X@w1) * (X@w3), gathered rows ----------------
// global_load_lds staging (m97 structure): linear LDS [128][32], 2 barriers/K-step.
// (256,4): 4 blocks/CU (LDS 24KB*4=96KB, VGPR 104<=128) — R5 was latency-bound at 21% occ.
__global__ __launch_bounds__(256,4) void k_gemmA(const bf16* __restrict__ xb,
    const bf16* __restrict__ w1T, const bf16* __restrict__ w3T,
    const int* __restrict__ ntiles, const int* __restrict__ te,
    const int* __restrict__ tb, const int* __restrict__ ts,
    const int* __restrict__ token_list, bf16* __restrict__ H){
  int tile = blockIdx.x;
  if(tile >= *ntiles) return;
  int e = te[tile], base = tb[tile], send = ts[tile];
  int f0 = blockIdx.y*128;
  __shared__ short As[128*32];
  __shared__ short B1s[128*32];
  __shared__ short B3s[128*32];
  int tid = threadIdx.x;
  // staging: instr i covers flat elems i*2048 + tid*8 -> row=i*64+(tid>>2), col=(tid&3)*8
  int srow0 = tid>>2, srow1 = 64 + (tid>>2), scol = (tid&3)*8;
  int r0g = base + srow0, r1g = base + srow1;
  int tok0 = token_list[(r0g < send) ? r0g : base];
  int tok1 = token_list[(r1g < send) ? r1g : base];
  const short* gA0  = (const short*)xb + (size_t)tok0*DIM + scol;
  const short* gA1  = (const short*)xb + (size_t)tok1*DIM + scol;
  const short* gB10 = (const short*)w1T + ((size_t)e*FDIM + f0 + srow0)*DIM + scol;
  const short* gB11 = (const short*)w1T + ((size_t)e*FDIM + f0 + srow1)*DIM + scol;
  const short* gB30 = (const short*)w3T + ((size_t)e*FDIM + f0 + srow0)*DIM + scol;
  const short* gB31 = (const short*)w3T + ((size_t)e*FDIM + f0 + srow1)*DIM + scol;
  char* lA  = (char*)As  + tid*16;
  char* lB1 = (char*)B1s + tid*16;
  char* lB3 = (char*)B3s + tid*16;
  int wid = tid>>6, lane = tid&63;
  int wr = wid>>1, wc = wid&1;
  int lrow = lane&15, lk = (lane>>4)<<3;
  f32x4 acc1[4][4] = {};
  f32x4 acc3[4][4] = {};
  for(int d0=0; d0<DIM; d0+=32){
    __syncthreads();                       // prev-iter fragment reads complete
    g2l16(gA0  + d0, lA);
    g2l16(gA1  + d0, lA  + 4096);
    g2l16(gB10 + d0, lB1);
    g2l16(gB11 + d0, lB1 + 4096);
    g2l16(gB30 + d0, lB3);
    g2l16(gB31 + d0, lB3 + 4096);
    __syncthreads();                       // vmcnt(0) drained before barrier
    bf16x8 af[4], bf1[4], bf3[4];
    #pragma unroll
    for(int m=0;m<4;m++) af[m] = *(const bf16x8*)&As[(wr*64+m*16+lrow)*32 + lk];
    #pragma unroll
    for(int n=0;n<4;n++){ bf1[n] = *(const bf16x8*)&B1s[(wc*64+n*16+lrow)*32 + lk];
                          bf3[n] = *(const bf16x8*)&B3s[(wc*64+n*16+lrow)*32 + lk]; }
    #pragma unroll
    for(int m=0;m<4;m++){
      #pragma unroll
      for(int n=0;n<4;n++){
        acc1[m][n] = __builtin_amdgcn_mfma_f32_16x16x32_bf16(af[m], bf1[n], acc1[m][n], 0,0,0);
        acc3[m][n] = __builtin_amdgcn_mfma_f32_16x16x32_bf16(af[m], bf3[n], acc3[m][n], 0,0,0);
      }
    }
  }
  #pragma unroll
  for(int m=0;m<4;m++){
    int r0 = base + wr*64 + m*16 + ((lane>>4)<<2);
    #pragma unroll
    for(int n=0;n<4;n++){
      int col = f0 + wc*64 + n*16 + lrow;
      #pragma unroll
      for(int j=0;j<4;j++){
        if(r0+j < send){
          float a = acc1[m][n][j];
          float h = a * (1.f/(1.f+__expf(-a))) * acc3[m][n][j];
          ((short*)H)[(size_t)(r0+j)*FDIM + col] = f2bf(h);
        }
      }
    }
  }
}

// ---------------- GEMM B: O[pos] = H[pos] @ w2  (no atomics) ----------------
__global__ __launch_bounds__(256,4) void k_gemmB(const bf16* __restrict__ H,
    const bf16* __restrict__ w2T, const int* __restrict__ ntiles,
    const int* __restrict__ te, const int* __restrict__ tb,
    const int* __restrict__ ts, bf16* __restrict__ O){
  int tile = blockIdx.x;
  if(tile >= *ntiles) return;
  int e = te[tile], base = tb[tile], send = ts[tile];
  int n0 = blockIdx.y*128;
  __shared__ short As[128*32];
  __shared__ short Bs[128*32];
  int tid = threadIdx.x;
  int srow0 = tid>>2, srow1 = 64 + (tid>>2), scol = (tid&3)*8;
  int r0g = base + srow0, r1g = base + srow1;
  int ar0 = (r0g < send) ? r0g : base;
  int ar1 = (r1g < send) ? r1g : base;
  const short* gA0 = (const short*)H + (size_t)ar0*FDIM + scol;
  const short* gA1 = (const short*)H + (size_t)ar1*FDIM + scol;
  const short* gB0 = (const short*)w2T + ((size_t)e*DIM + n0 + srow0)*FDIM + scol;
  const short* gB1 = (const short*)w2T + ((size_t)e*DIM + n0 + srow1)*FDIM + scol;
  char* lA = (char*)As + tid*16;
  char* lB = (char*)Bs + tid*16;
  int wid = tid>>6, lane = tid&63, wr = wid>>1, wc = wid&1;
  int lrow = lane&15, lk = (lane>>4)<<3;
  f32x4 acc[4][4] = {};
  for(int k0=0; k0<FDIM; k0+=32){
    __syncthreads();
    g2l16(gA0 + k0, lA);
    g2l16(gA1 + k0, lA + 4096);
    g2l16(gB0 + k0, lB);
    g2l16(gB1 + k0, lB + 4096);
    __syncthreads();
    bf16x8 af[4], bfr[4];
    #pragma unroll
    for(int m=0;m<4;m++) af[m]  = *(const bf16x8*)&As[(wr*64+m*16+lrow)*32 + lk];
    #pragma unroll
    for(int n=0;n<4;n++) bfr[n] = *(const bf16x8*)&Bs[(wc*64+n*16+lrow)*32 + lk];
    #pragma unroll
    for(int m=0;m<4;m++){
      #pragma unroll
      for(int n=0;n<4;n++)
        acc[m][n] = __builtin_amdgcn_mfma_f32_16x16x32_bf16(af[m], bfr[n], acc[m][n], 0,0,0);
    }
  }
  #pragma unroll
  for(int m=0;m<4;m++){
    #pragma unroll
    for(int j=0;j<4;j++){
      int r2 = base + wr*64 + m*16 + ((lane>>4)<<2) + j;
      if(r2 < send){
        #pragma unroll
        for(int n=0;n<4;n++){
          int col = n0 + wc*64 + n*16 + lrow;
          ((short*)O)[(size_t)r2*DIM + col] = f2bf(acc[m][n][j]);
        }
      }
    }
  }
}

// ---------------- combine: out[t] = w0*O[p0] + w1*O[p1] ----------------
__global__ __launch_bounds__(256) void k_combine(const bf16* __restrict__ O,
    const int* __restrict__ posmap, const float* __restrict__ tw,
    float* __restrict__ out){
  int lane = threadIdx.x & 63, wid = threadIdx.x >> 6;
  int t = blockIdx.x*4 + wid;
  int p0 = posmap[2*t], p1 = posmap[2*t+1];
  float w0 = tw[2*t], w1 = tw[2*t+1];
  s16x8 a = *(const s16x8*)((const short*)O + (size_t)p0*DIM + lane*8);
  s16x8 b = *(const s16x8*)((const short*)O + (size_t)p1*DIM + lane*8);
  f32x4 r0, r1;
  #pragma unroll
  for(int j=0;j<4;j++) r0[j] = w0*bf2f(a[j]) + w1*bf2f(b[j]);
  #pragma unroll
  for(int j=0;j<4;j++) r1[j] = w0*bf2f(a[4+j]) + w1*bf2f(b[4+j]);
  float* o = out + (size_t)t*DIM + lane*8;
  *(f32x4*)o = r0;
  *(f32x4*)(o+4) = r1;
}

extern "C" void kernel_launch(void* const* d_in, const int* in_sizes, int n_in,
                              void* d_out, int out_size, void* d_ws, size_t ws_size,
                              hipStream_t stream){
  const float* x  = (const float*)d_in[0];
  const float* gw = (const float*)d_in[1];
  const float* w1 = (const float*)d_in[2];
  const float* w2 = (const float*)d_in[3];
  const float* w3 = (const float*)d_in[4];
  float* out = (float*)d_out;
  char* ws = (char*)d_ws;

  int* cw = (int*)ws;
  int* counts = cw;                 // 8
  int* fill   = cw + 8;             // 8
  int* offsets= cw + 16;            // 8
  int* ntiles = cw + 24;            // 1 (+pad)
  int* te = cw + 32;                // 264
  int* tb = cw + 296;               // 264
  int* ts = cw + 560;               // 264
  int* tidx       = cw + 824;                 // PAIRS
  int* token_list = cw + 824 + PAIRS;         // PAIRS
  int* posmap     = cw + 824 + 2*PAIRS;       // PAIRS
  float* tw       = (float*)(cw + 824 + 3*PAIRS); // PAIRS

  const size_t MB = 1u<<20;
  bf16* xb  = (bf16*)(ws + 1*MB);           // 16 MiB
  bf16* w1T = (bf16*)(ws + 17*MB);          // 16 MiB
  bf16* w3T = (bf16*)(ws + 33*MB);          // 16 MiB
  bf16* w2T = (bf16*)(ws + 49*MB);          // 16 MiB
  bf16* Hbuf= (bf16*)(ws + 65*MB);          // PAIRS*FDIM*2 = 128 MiB
  bf16* Obuf= (bf16*)(ws + 17*MB);          // aliases w1T+w3T (32 MiB), dead by gemmB
  size_t needed = 65*MB + (size_t)PAIRS*FDIM*2u;
  if(ws_size < needed) return;

  hipMemsetAsync(d_ws, 0, 64, stream);      // counts + fill

  k_gate<<<N_TOK/8, 512, 0, stream>>>(x, gw, tidx, tw);
  k_count<<<PAIRS/1024, 256, 0, stream>>>(tidx, counts);
  k_route<<<1, 64, 0, stream>>>(counts, offsets, ntiles, te, tb, ts);
  k_scatter<<<PAIRS/256, 256, 0, stream>>>(tidx, offsets, fill, token_list, posmap);
  k_cast<<<(N_TOK*DIM/8)/256, 256, 0, stream>>>(x, xb);
  k_transpose<<<dim3(FDIM/32, DIM/32, NEXP), 256, 0, stream>>>(w1, w1T, DIM, FDIM);
  k_transpose<<<dim3(FDIM/32, DIM/32, NEXP), 256, 0, stream>>>(w3, w3T, DIM, FDIM);
  k_transpose<<<dim3(DIM/32, FDIM/32, NEXP), 256, 0, stream>>>(w2, w2T, FDIM, DIM);
  k_gemmA<<<dim3(MAX_TILES, FDIM/128), 256, 0, stream>>>(xb, w1T, w3T, ntiles, te, tb, ts, token_list, Hbuf);
  k_gemmB<<<dim3(MAX_TILES, DIM/128), 256, 0, stream>>>(Hbuf, w2T, ntiles, te, tb, ts, Obuf);
  k_combine<<<N_TOK/4, 256, 0, stream>>>(Obuf, posmap, tw, out);
}

// Round 7
// 815.920 us; speedup vs baseline: 2.5631x; 2.5631x over previous
//
#include <hip/hip_runtime.h>
#include <hip/hip_bf16.h>
#include <math.h>

#define N_TOK 16384
#define DIM   512
#define FDIM  2048
#define NEXP  8
#define TOPK  2
#define PAIRS (N_TOK*TOPK)             // 32768
#define MAX_TILES (PAIRS/128 + NEXP)   // 264

typedef __hip_bfloat16 bf16;
typedef __attribute__((ext_vector_type(8))) short bf16x8;
typedef __attribute__((ext_vector_type(4))) float f32x4;
typedef __attribute__((ext_vector_type(8))) short s16x8;

__device__ __forceinline__ short f2bf(float f){
  union { float f; unsigned u; } v; v.f = f;
  unsigned r = v.u + 0x7fffu + ((v.u >> 16) & 1u);
  return (short)(r >> 16);
}
__device__ __forceinline__ float bf2f(short s){
  union { unsigned u; float f; } v; v.u = ((unsigned)(unsigned short)s) << 16;
  return v.f;
}
// async global->LDS, 16B per lane. LDS dest = wave-uniform base + lane*16.
__device__ __forceinline__ void g2l16(const void* g, void* l){
  __builtin_amdgcn_global_load_lds(
      (const __attribute__((address_space(1))) unsigned int*)g,
      (__attribute__((address_space(3))) unsigned int*)l, 16, 0, 0);
}

// ---------------- gating: fp32 logits, top-2, softmax. NO global atomics ----------------
__global__ __launch_bounds__(512) void k_gate(const float* __restrict__ x,
    const float* __restrict__ gw, int* __restrict__ tidx, float* __restrict__ tw){
  __shared__ float gwT[NEXP][DIM];     // 16 KB, transposed: gwT[e][d]
  int tid = threadIdx.x;
  #pragma unroll
  for(int i=0;i<8;i++){
    int idx = tid + 512*i;             // 4096 floats
    gwT[idx&7][idx>>3] = gw[idx];
  }
  __syncthreads();
  int lane = tid & 63, wid = tid >> 6;
  int t = blockIdx.x*8 + wid;
  const float* xr = x + (size_t)t*DIM;
  float acc[NEXP];
  #pragma unroll
  for(int e=0;e<NEXP;e++) acc[e]=0.f;
  #pragma unroll
  for(int c=0;c<8;c++){
    float xv = xr[c*64 + lane];        // coalesced 256B per wave-load
    #pragma unroll
    for(int e=0;e<NEXP;e++) acc[e] += xv * gwT[e][c*64+lane];  // stride-1: conflict-free
  }
  #pragma unroll
  for(int off=32; off; off>>=1){
    #pragma unroll
    for(int e=0;e<NEXP;e++) acc[e] += __shfl_xor(acc[e], off);
  }
  if(lane==0){
    int e0=0; float v0=acc[0];
    #pragma unroll
    for(int e=1;e<NEXP;e++) if(acc[e]>v0){v0=acc[e]; e0=e;}
    int e1=-1; float v1=-1e30f;
    #pragma unroll
    for(int e=0;e<NEXP;e++) if(e!=e0 && acc[e]>v1){v1=acc[e]; e1=e;}
    float z = expf(v1-v0);
    float w0 = 1.f/(1.f+z);
    tidx[t*2]=e0; tidx[t*2+1]=e1;
    tw[t*2]=w0; tw[t*2+1]=1.f-w0;
  }
}

// ---------------- histogram: 8 global atomics per block ----------------
__global__ __launch_bounds__(256) void k_count(const int* __restrict__ tidx,
                                               int* __restrict__ counts){
  __shared__ int h[NEXP];
  if(threadIdx.x<NEXP) h[threadIdx.x]=0;
  __syncthreads();
  int i0 = blockIdx.x*1024 + threadIdx.x;
  #pragma unroll
  for(int k=0;k<4;k++) atomicAdd(&h[tidx[i0 + 256*k]], 1);
  __syncthreads();
  if(threadIdx.x<NEXP) atomicAdd(&counts[threadIdx.x], h[threadIdx.x]);
}

// ---------------- routing tables: dense offsets, ragged tiles ----------------
__global__ void k_route(const int* __restrict__ counts, int* __restrict__ offsets,
    int* __restrict__ ntiles, int* __restrict__ te, int* __restrict__ tb,
    int* __restrict__ ts){
  if(threadIdx.x==0){
    int off=0, nt=0;
    for(int e=0;e<NEXP;e++){
      offsets[e]=off;
      int c=counts[e];
      int tiles=(c+127)>>7;
      for(int i=0;i<tiles;i++){ te[nt]=e; tb[nt]=off+(i<<7); ts[nt]=off+c; nt++; }
      off += c;
    }
    *ntiles=nt;
  }
}

// ---------------- scatter: block-level reservation, dense positions ----------------
__global__ __launch_bounds__(256) void k_scatter(const int* __restrict__ tidx,
    const int* __restrict__ offsets, int* __restrict__ fill,
    int* __restrict__ token_list, int* __restrict__ posmap){
  __shared__ int lcnt[NEXP], lbase[NEXP];
  if(threadIdx.x<NEXP) lcnt[threadIdx.x]=0;
  __syncthreads();
  int i = blockIdx.x*256 + threadIdx.x;
  int e = tidx[i];
  int rank = atomicAdd(&lcnt[e], 1);          // LDS atomic: cheap
  __syncthreads();
  if(threadIdx.x<NEXP) lbase[threadIdx.x] = atomicAdd(&fill[threadIdx.x], lcnt[threadIdx.x]);
  __syncthreads();
  int pos = offsets[e] + lbase[e] + rank;
  token_list[pos] = i>>1;
  posmap[i] = pos;
}

// ---------------- fp32 -> bf16 cast (x) ----------------
__global__ __launch_bounds__(256) void k_cast(const float* __restrict__ x,
                                              bf16* __restrict__ xb){
  int i = blockIdx.x*256 + threadIdx.x;
  const float* p = x + (size_t)i*8;
  f32x4 a = *(const f32x4*)p;
  f32x4 b = *(const f32x4*)(p+4);
  s16x8 r;
  r[0]=f2bf(a[0]); r[1]=f2bf(a[1]); r[2]=f2bf(a[2]); r[3]=f2bf(a[3]);
  r[4]=f2bf(b[0]); r[5]=f2bf(b[1]); r[6]=f2bf(b[2]); r[7]=f2bf(b[3]);
  *(s16x8*)((short*)xb + (size_t)i*8) = r;
}

// ---------------- transpose+cast: src [R][C] f32 -> dst [C][R] bf16 ----------------
__global__ __launch_bounds__(256) void k_transpose(const float* __restrict__ src,
    bf16* __restrict__ dst, int R, int C){
  __shared__ float tile[32][33];
  const float* s = src + (size_t)blockIdx.z*R*C;
  short* d = (short*)dst + (size_t)blockIdx.z*R*C;
  int c0 = blockIdx.x*32, r0 = blockIdx.y*32;
  int tx = threadIdx.x & 31, ty = threadIdx.x >> 5;
  #pragma unroll
  for(int i=0;i<4;i++) tile[ty+8*i][tx] = s[(size_t)(r0+ty+8*i)*C + c0+tx];
  __syncthreads();
  #pragma unroll
  for(int i=0;i<4;i++) d[(size_t)(c0+ty+8*i)*R + r0+tx] = f2bf(tile[tx][ty+8*i]);
}

// ---------------- GEMM A: H[pos] = silu(X@w1) * (X@w3), gathered rows ----------------
// global_load_lds staging (m97 structure): linear LDS [128][32], 2 barriers/K-step.
// (256,3): 3 blocks/CU, VGPR budget ~170/wave -> 104 arch + 64 acc fits, NO spill.
// R6 lesson: (256,4) capped unified VGPR+AGPR at 128 -> accumulator spill to scratch,
// 8.2 GB HBM traffic/dispatch, MfmaUtil 3%. Audit arch+acc regs vs 512/(waves/SIMD).
__global__ __launch_bounds__(256,3) void k_gemmA(const bf16* __restrict__ xb,
    const bf16* __restrict__ w1T, const bf16* __restrict__ w3T,
    const int* __restrict__ ntiles, const int* __restrict__ te,
    const int* __restrict__ tb, const int* __restrict__ ts,
    const int* __restrict__ token_list, bf16* __restrict__ H){
  int tile = blockIdx.x;
  if(tile >= *ntiles) return;
  int e = te[tile], base = tb[tile], send = ts[tile];
  int f0 = blockIdx.y*128;
  __shared__ short As[128*32];
  __shared__ short B1s[128*32];
  __shared__ short B3s[128*32];
  int tid = threadIdx.x;
  // staging: instr i covers flat elems i*2048 + tid*8 -> row=i*64+(tid>>2), col=(tid&3)*8
  int srow0 = tid>>2, srow1 = 64 + (tid>>2), scol = (tid&3)*8;
  int r0g = base + srow0, r1g = base + srow1;
  int tok0 = token_list[(r0g < send) ? r0g : base];
  int tok1 = token_list[(r1g < send) ? r1g : base];
  const short* gA0  = (const short*)xb + (size_t)tok0*DIM + scol;
  const short* gA1  = (const short*)xb + (size_t)tok1*DIM + scol;
  const short* gB10 = (const short*)w1T + ((size_t)e*FDIM + f0 + srow0)*DIM + scol;
  const short* gB11 = (const short*)w1T + ((size_t)e*FDIM + f0 + srow1)*DIM + scol;
  const short* gB30 = (const short*)w3T + ((size_t)e*FDIM + f0 + srow0)*DIM + scol;
  const short* gB31 = (const short*)w3T + ((size_t)e*FDIM + f0 + srow1)*DIM + scol;
  char* lA  = (char*)As  + tid*16;
  char* lB1 = (char*)B1s + tid*16;
  char* lB3 = (char*)B3s + tid*16;
  int wid = tid>>6, lane = tid&63;
  int wr = wid>>1, wc = wid&1;
  int lrow = lane&15, lk = (lane>>4)<<3;
  f32x4 acc1[4][4] = {};
  f32x4 acc3[4][4] = {};
  for(int d0=0; d0<DIM; d0+=32){
    __syncthreads();                       // prev-iter fragment reads complete
    g2l16(gA0  + d0, lA);
    g2l16(gA1  + d0, lA  + 4096);
    g2l16(gB10 + d0, lB1);
    g2l16(gB11 + d0, lB1 + 4096);
    g2l16(gB30 + d0, lB3);
    g2l16(gB31 + d0, lB3 + 4096);
    __syncthreads();                       // vmcnt(0) drained before barrier
    bf16x8 af[4], bf1[4], bf3[4];
    #pragma unroll
    for(int m=0;m<4;m++) af[m] = *(const bf16x8*)&As[(wr*64+m*16+lrow)*32 + lk];
    #pragma unroll
    for(int n=0;n<4;n++){ bf1[n] = *(const bf16x8*)&B1s[(wc*64+n*16+lrow)*32 + lk];
                          bf3[n] = *(const bf16x8*)&B3s[(wc*64+n*16+lrow)*32 + lk]; }
    #pragma unroll
    for(int m=0;m<4;m++){
      #pragma unroll
      for(int n=0;n<4;n++){
        acc1[m][n] = __builtin_amdgcn_mfma_f32_16x16x32_bf16(af[m], bf1[n], acc1[m][n], 0,0,0);
        acc3[m][n] = __builtin_amdgcn_mfma_f32_16x16x32_bf16(af[m], bf3[n], acc3[m][n], 0,0,0);
      }
    }
  }
  #pragma unroll
  for(int m=0;m<4;m++){
    int r0 = base + wr*64 + m*16 + ((lane>>4)<<2);
    #pragma unroll
    for(int n=0;n<4;n++){
      int col = f0 + wc*64 + n*16 + lrow;
      #pragma unroll
      for(int j=0;j<4;j++){
        if(r0+j < send){
          float a = acc1[m][n][j];
          float h = a * (1.f/(1.f+__expf(-a))) * acc3[m][n][j];
          ((short*)H)[(size_t)(r0+j)*FDIM + col] = f2bf(h);
        }
      }
    }
  }
}

// ---------------- GEMM B: O[pos] = H[pos] @ w2  (no atomics) ----------------
__global__ __launch_bounds__(256,3) void k_gemmB(const bf16* __restrict__ H,
    const bf16* __restrict__ w2T, const int* __restrict__ ntiles,
    const int* __restrict__ te, const int* __restrict__ tb,
    const int* __restrict__ ts, bf16* __restrict__ O){
  int tile = blockIdx.x;
  if(tile >= *ntiles) return;
  int e = te[tile], base = tb[tile], send = ts[tile];
  int n0 = blockIdx.y*128;
  __shared__ short As[128*32];
  __shared__ short Bs[128*32];
  int tid = threadIdx.x;
  int srow0 = tid>>2, srow1 = 64 + (tid>>2), scol = (tid&3)*8;
  int r0g = base + srow0, r1g = base + srow1;
  int ar0 = (r0g < send) ? r0g : base;
  int ar1 = (r1g < send) ? r1g : base;
  const short* gA0 = (const short*)H + (size_t)ar0*FDIM + scol;
  const short* gA1 = (const short*)H + (size_t)ar1*FDIM + scol;
  const short* gB0 = (const short*)w2T + ((size_t)e*DIM + n0 + srow0)*FDIM + scol;
  const short* gB1 = (const short*)w2T + ((size_t)e*DIM + n0 + srow1)*FDIM + scol;
  char* lA = (char*)As + tid*16;
  char* lB = (char*)Bs + tid*16;
  int wid = tid>>6, lane = tid&63, wr = wid>>1, wc = wid&1;
  int lrow = lane&15, lk = (lane>>4)<<3;
  f32x4 acc[4][4] = {};
  for(int k0=0; k0<FDIM; k0+=32){
    __syncthreads();
    g2l16(gA0 + k0, lA);
    g2l16(gA1 + k0, lA + 4096);
    g2l16(gB0 + k0, lB);
    g2l16(gB1 + k0, lB + 4096);
    __syncthreads();
    bf16x8 af[4], bfr[4];
    #pragma unroll
    for(int m=0;m<4;m++) af[m]  = *(const bf16x8*)&As[(wr*64+m*16+lrow)*32 + lk];
    #pragma unroll
    for(int n=0;n<4;n++) bfr[n] = *(const bf16x8*)&Bs[(wc*64+n*16+lrow)*32 + lk];
    #pragma unroll
    for(int m=0;m<4;m++){
      #pragma unroll
      for(int n=0;n<4;n++)
        acc[m][n] = __builtin_amdgcn_mfma_f32_16x16x32_bf16(af[m], bfr[n], acc[m][n], 0,0,0);
    }
  }
  #pragma unroll
  for(int m=0;m<4;m++){
    #pragma unroll
    for(int j=0;j<4;j++){
      int r2 = base + wr*64 + m*16 + ((lane>>4)<<2) + j;
      if(r2 < send){
        #pragma unroll
        for(int n=0;n<4;n++){
          int col = n0 + wc*64 + n*16 + lrow;
          ((short*)O)[(size_t)r2*DIM + col] = f2bf(acc[m][n][j]);
        }
      }
    }
  }
}

// ---------------- combine: out[t] = w0*O[p0] + w1*O[p1] ----------------
__global__ __launch_bounds__(256) void k_combine(const bf16* __restrict__ O,
    const int* __restrict__ posmap, const float* __restrict__ tw,
    float* __restrict__ out){
  int lane = threadIdx.x & 63, wid = threadIdx.x >> 6;
  int t = blockIdx.x*4 + wid;
  int p0 = posmap[2*t], p1 = posmap[2*t+1];
  float w0 = tw[2*t], w1 = tw[2*t+1];
  s16x8 a = *(const s16x8*)((const short*)O + (size_t)p0*DIM + lane*8);
  s16x8 b = *(const s16x8*)((const short*)O + (size_t)p1*DIM + lane*8);
  f32x4 r0, r1;
  #pragma unroll
  for(int j=0;j<4;j++) r0[j] = w0*bf2f(a[j]) + w1*bf2f(b[j]);
  #pragma unroll
  for(int j=0;j<4;j++) r1[j] = w0*bf2f(a[4+j]) + w1*bf2f(b[4+j]);
  float* o = out + (size_t)t*DIM + lane*8;
  *(f32x4*)o = r0;
  *(f32x4*)(o+4) = r1;
}

extern "C" void kernel_launch(void* const* d_in, const int* in_sizes, int n_in,
                              void* d_out, int out_size, void* d_ws, size_t ws_size,
                              hipStream_t stream){
  const float* x  = (const float*)d_in[0];
  const float* gw = (const float*)d_in[1];
  const float* w1 = (const float*)d_in[2];
  const float* w2 = (const float*)d_in[3];
  const float* w3 = (const float*)d_in[4];
  float* out = (float*)d_out;
  char* ws = (char*)d_ws;

  int* cw = (int*)ws;
  int* counts = cw;                 // 8
  int* fill   = cw + 8;             // 8
  int* offsets= cw + 16;            // 8
  int* ntiles = cw + 24;            // 1 (+pad)
  int* te = cw + 32;                // 264
  int* tb = cw + 296;               // 264
  int* ts = cw + 560;               // 264
  int* tidx       = cw + 824;                 // PAIRS
  int* token_list = cw + 824 + PAIRS;         // PAIRS
  int* posmap     = cw + 824 + 2*PAIRS;       // PAIRS
  float* tw       = (float*)(cw + 824 + 3*PAIRS); // PAIRS

  const size_t MB = 1u<<20;
  bf16* xb  = (bf16*)(ws + 1*MB);           // 16 MiB
  bf16* w1T = (bf16*)(ws + 17*MB);          // 16 MiB
  bf16* w3T = (bf16*)(ws + 33*MB);          // 16 MiB
  bf16* w2T = (bf16*)(ws + 49*MB);          // 16 MiB
  bf16* Hbuf= (bf16*)(ws + 65*MB);          // PAIRS*FDIM*2 = 128 MiB
  bf16* Obuf= (bf16*)(ws + 17*MB);          // aliases w1T+w3T (32 MiB), dead by gemmB
  size_t needed = 65*MB + (size_t)PAIRS*FDIM*2u;
  if(ws_size < needed) return;

  hipMemsetAsync(d_ws, 0, 64, stream);      // counts + fill

  k_gate<<<N_TOK/8, 512, 0, stream>>>(x, gw, tidx, tw);
  k_count<<<PAIRS/1024, 256, 0, stream>>>(tidx, counts);
  k_route<<<1, 64, 0, stream>>>(counts, offsets, ntiles, te, tb, ts);
  k_scatter<<<PAIRS/256, 256, 0, stream>>>(tidx, offsets, fill, token_list, posmap);
  k_cast<<<(N_TOK*DIM/8)/256, 256, 0, stream>>>(x, xb);
  k_transpose<<<dim3(FDIM/32, DIM/32, NEXP), 256, 0, stream>>>(w1, w1T, DIM, FDIM);
  k_transpose<<<dim3(FDIM/32, DIM/32, NEXP), 256, 0, stream>>>(w3, w3T, DIM, FDIM);
  k_transpose<<<dim3(DIM/32, FDIM/32, NEXP), 256, 0, stream>>>(w2, w2T, FDIM, DIM);
  k_gemmA<<<dim3(MAX_TILES, FDIM/128), 256, 0, stream>>>(xb, w1T, w3T, ntiles, te, tb, ts, token_list, Hbuf);
  k_gemmB<<<dim3(MAX_TILES, DIM/128), 256, 0, stream>>>(Hbuf, w2T, ntiles, te, tb, ts, Obuf);
  k_combine<<<N_TOK/4, 256, 0, stream>>>(Obuf, posmap, tw, out);
}

// Round 8
// 589.827 us; speedup vs baseline: 3.5455x; 1.3833x over previous
//
#include <hip/hip_runtime.h>
#include <hip/hip_bf16.h>
#include <math.h>

#define N_TOK 16384
#define DIM   512
#define FDIM  2048
#define NEXP  8
#define TOPK  2
#define PAIRS (N_TOK*TOPK)             // 32768
#define MAX_TILES (PAIRS/128 + NEXP)   // 264

typedef __hip_bfloat16 bf16;
typedef __attribute__((ext_vector_type(8))) short bf16x8;
typedef __attribute__((ext_vector_type(4))) float f32x4;
typedef __attribute__((ext_vector_type(8))) short s16x8;

__device__ __forceinline__ short f2bf(float f){
  union { float f; unsigned u; } v; v.f = f;
  unsigned r = v.u + 0x7fffu + ((v.u >> 16) & 1u);
  return (short)(r >> 16);
}
__device__ __forceinline__ float bf2f(short s){
  union { unsigned u; float f; } v; v.u = ((unsigned)(unsigned short)s) << 16;
  return v.f;
}
// async global->LDS, 16B per lane. LDS dest = wave-uniform base + lane*16.
__device__ __forceinline__ void g2l16(const void* g, void* l){
  __builtin_amdgcn_global_load_lds(
      (const __attribute__((address_space(1))) unsigned int*)g,
      (__attribute__((address_space(3))) unsigned int*)l, 16, 0, 0);
}

// ---------------- gating: fp32 logits, top-2, softmax. NO global atomics ----------------
__global__ __launch_bounds__(512) void k_gate(const float* __restrict__ x,
    const float* __restrict__ gw, int* __restrict__ tidx, float* __restrict__ tw){
  __shared__ float gwT[NEXP][DIM];     // 16 KB, transposed: gwT[e][d]
  int tid = threadIdx.x;
  #pragma unroll
  for(int i=0;i<8;i++){
    int idx = tid + 512*i;             // 4096 floats
    gwT[idx&7][idx>>3] = gw[idx];
  }
  __syncthreads();
  int lane = tid & 63, wid = tid >> 6;
  int t = blockIdx.x*8 + wid;
  const float* xr = x + (size_t)t*DIM;
  float acc[NEXP];
  #pragma unroll
  for(int e=0;e<NEXP;e++) acc[e]=0.f;
  #pragma unroll
  for(int c=0;c<8;c++){
    float xv = xr[c*64 + lane];        // coalesced 256B per wave-load
    #pragma unroll
    for(int e=0;e<NEXP;e++) acc[e] += xv * gwT[e][c*64+lane];  // stride-1: conflict-free
  }
  #pragma unroll
  for(int off=32; off; off>>=1){
    #pragma unroll
    for(int e=0;e<NEXP;e++) acc[e] += __shfl_xor(acc[e], off);
  }
  if(lane==0){
    int e0=0; float v0=acc[0];
    #pragma unroll
    for(int e=1;e<NEXP;e++) if(acc[e]>v0){v0=acc[e]; e0=e;}
    int e1=-1; float v1=-1e30f;
    #pragma unroll
    for(int e=0;e<NEXP;e++) if(e!=e0 && acc[e]>v1){v1=acc[e]; e1=e;}
    float z = expf(v1-v0);
    float w0 = 1.f/(1.f+z);
    tidx[t*2]=e0; tidx[t*2+1]=e1;
    tw[t*2]=w0; tw[t*2+1]=1.f-w0;
  }
}

// ---------------- histogram: 8 global atomics per block ----------------
__global__ __launch_bounds__(256) void k_count(const int* __restrict__ tidx,
                                               int* __restrict__ counts){
  __shared__ int h[NEXP];
  if(threadIdx.x<NEXP) h[threadIdx.x]=0;
  __syncthreads();
  int i0 = blockIdx.x*1024 + threadIdx.x;
  #pragma unroll
  for(int k=0;k<4;k++) atomicAdd(&h[tidx[i0 + 256*k]], 1);
  __syncthreads();
  if(threadIdx.x<NEXP) atomicAdd(&counts[threadIdx.x], h[threadIdx.x]);
}

// ---------------- routing tables: dense offsets, ragged tiles ----------------
__global__ void k_route(const int* __restrict__ counts, int* __restrict__ offsets,
    int* __restrict__ ntiles, int* __restrict__ te, int* __restrict__ tb,
    int* __restrict__ ts){
  if(threadIdx.x==0){
    int off=0, nt=0;
    for(int e=0;e<NEXP;e++){
      offsets[e]=off;
      int c=counts[e];
      int tiles=(c+127)>>7;
      for(int i=0;i<tiles;i++){ te[nt]=e; tb[nt]=off+(i<<7); ts[nt]=off+c; nt++; }
      off += c;
    }
    *ntiles=nt;
  }
}

// ---------------- scatter: block-level reservation, dense positions ----------------
__global__ __launch_bounds__(256) void k_scatter(const int* __restrict__ tidx,
    const int* __restrict__ offsets, int* __restrict__ fill,
    int* __restrict__ token_list, int* __restrict__ posmap){
  __shared__ int lcnt[NEXP], lbase[NEXP];
  if(threadIdx.x<NEXP) lcnt[threadIdx.x]=0;
  __syncthreads();
  int i = blockIdx.x*256 + threadIdx.x;
  int e = tidx[i];
  int rank = atomicAdd(&lcnt[e], 1);          // LDS atomic: cheap
  __syncthreads();
  if(threadIdx.x<NEXP) lbase[threadIdx.x] = atomicAdd(&fill[threadIdx.x], lcnt[threadIdx.x]);
  __syncthreads();
  int pos = offsets[e] + lbase[e] + rank;
  token_list[pos] = i>>1;
  posmap[i] = pos;
}

// ---------------- fp32 -> bf16 cast (x) ----------------
__global__ __launch_bounds__(256) void k_cast(const float* __restrict__ x,
                                              bf16* __restrict__ xb){
  int i = blockIdx.x*256 + threadIdx.x;
  const float* p = x + (size_t)i*8;
  f32x4 a = *(const f32x4*)p;
  f32x4 b = *(const f32x4*)(p+4);
  s16x8 r;
  r[0]=f2bf(a[0]); r[1]=f2bf(a[1]); r[2]=f2bf(a[2]); r[3]=f2bf(a[3]);
  r[4]=f2bf(b[0]); r[5]=f2bf(b[1]); r[6]=f2bf(b[2]); r[7]=f2bf(b[3]);
  *(s16x8*)((short*)xb + (size_t)i*8) = r;
}

// ---------------- transpose+cast: src [R][C] f32 -> dst [C][R] bf16 ----------------
__global__ __launch_bounds__(256) void k_transpose(const float* __restrict__ src,
    bf16* __restrict__ dst, int R, int C){
  __shared__ float tile[32][33];
  const float* s = src + (size_t)blockIdx.z*R*C;
  short* d = (short*)dst + (size_t)blockIdx.z*R*C;
  int c0 = blockIdx.x*32, r0 = blockIdx.y*32;
  int tx = threadIdx.x & 31, ty = threadIdx.x >> 5;
  #pragma unroll
  for(int i=0;i<4;i++) tile[ty+8*i][tx] = s[(size_t)(r0+ty+8*i)*C + c0+tx];
  __syncthreads();
  #pragma unroll
  for(int i=0;i<4;i++) d[(size_t)(c0+ty+8*i)*R + r0+tx] = f2bf(tile[tx][ty+8*i]);
}

// ---------------- GEMM A: H[pos] = silu(X@w1) * (X@w3), gathered rows ----------------
// R7 lesson: 64x64-dual wave tile needs ~200 regs -> only 2 blocks/CU w/o spill.
// Reshape: wave = 64x32 dual (acc 64 + frags 32 + addr ~30 = ~125 regs), block =
// 128 rows x 64 f-cols, grid.y = FDIM/64. (256,3): budget 168 -> no spill, 3 blocks/CU.
__global__ __launch_bounds__(256,3) void k_gemmA(const bf16* __restrict__ xb,
    const bf16* __restrict__ w1T, const bf16* __restrict__ w3T,
    const int* __restrict__ ntiles, const int* __restrict__ te,
    const int* __restrict__ tb, const int* __restrict__ ts,
    const int* __restrict__ token_list, bf16* __restrict__ H){
  int tile = blockIdx.x;
  if(tile >= *ntiles) return;
  int e = te[tile], base = tb[tile], send = ts[tile];
  int f0 = blockIdx.y*64;
  __shared__ short As[128*32];    // 8 KB
  __shared__ short B1s[64*32];    // 4 KB
  __shared__ short B3s[64*32];    // 4 KB
  int tid = threadIdx.x;
  // staging: A instr i covers rows i*64+(tid>>2), col (tid&3)*8; B single instr rows 0-63
  int srow0 = tid>>2, srow1 = 64 + (tid>>2), scol = (tid&3)*8;
  int r0g = base + srow0, r1g = base + srow1;
  int tok0 = token_list[(r0g < send) ? r0g : base];
  int tok1 = token_list[(r1g < send) ? r1g : base];
  const short* gA0 = (const short*)xb + (size_t)tok0*DIM + scol;
  const short* gA1 = (const short*)xb + (size_t)tok1*DIM + scol;
  const short* gB1 = (const short*)w1T + ((size_t)e*FDIM + f0 + srow0)*DIM + scol;
  const short* gB3 = (const short*)w3T + ((size_t)e*FDIM + f0 + srow0)*DIM + scol;
  char* lA  = (char*)As  + tid*16;
  char* lB1 = (char*)B1s + tid*16;
  char* lB3 = (char*)B3s + tid*16;
  int wid = tid>>6, lane = tid&63;
  int wr = wid>>1, wc = wid&1;          // wave: rows wr*64, cols wc*32
  int lrow = lane&15, lk = (lane>>4)<<3;
  f32x4 acc1[4][2] = {};
  f32x4 acc3[4][2] = {};
  for(int d0=0; d0<DIM; d0+=32){
    __syncthreads();                       // prev-iter fragment reads complete
    g2l16(gA0 + d0, lA);
    g2l16(gA1 + d0, lA + 4096);
    g2l16(gB1 + d0, lB1);
    g2l16(gB3 + d0, lB3);
    __syncthreads();                       // vmcnt(0) drained before barrier
    bf16x8 af[4], b1f[2], b3f[2];
    #pragma unroll
    for(int m=0;m<4;m++) af[m] = *(const bf16x8*)&As[(wr*64+m*16+lrow)*32 + lk];
    #pragma unroll
    for(int n=0;n<2;n++){ b1f[n] = *(const bf16x8*)&B1s[(wc*32+n*16+lrow)*32 + lk];
                          b3f[n] = *(const bf16x8*)&B3s[(wc*32+n*16+lrow)*32 + lk]; }
    #pragma unroll
    for(int m=0;m<4;m++){
      #pragma unroll
      for(int n=0;n<2;n++){
        acc1[m][n] = __builtin_amdgcn_mfma_f32_16x16x32_bf16(af[m], b1f[n], acc1[m][n], 0,0,0);
        acc3[m][n] = __builtin_amdgcn_mfma_f32_16x16x32_bf16(af[m], b3f[n], acc3[m][n], 0,0,0);
      }
    }
  }
  #pragma unroll
  for(int m=0;m<4;m++){
    int r0 = base + wr*64 + m*16 + ((lane>>4)<<2);
    #pragma unroll
    for(int n=0;n<2;n++){
      int col = f0 + wc*32 + n*16 + lrow;
      #pragma unroll
      for(int j=0;j<4;j++){
        if(r0+j < send){
          float a = acc1[m][n][j];
          float h = a * (1.f/(1.f+__expf(-a))) * acc3[m][n][j];
          ((short*)H)[(size_t)(r0+j)*FDIM + col] = f2bf(h);
        }
      }
    }
  }
}

// ---------------- GEMM B: O[pos] = H[pos] @ w2  (no atomics) ----------------
// Same reshape: block 128 rows x 64 out-cols, grid.y = DIM/64 = 8; acc[4][2] ~90 regs.
__global__ __launch_bounds__(256,3) void k_gemmB(const bf16* __restrict__ H,
    const bf16* __restrict__ w2T, const int* __restrict__ ntiles,
    const int* __restrict__ te, const int* __restrict__ tb,
    const int* __restrict__ ts, bf16* __restrict__ O){
  int tile = blockIdx.x;
  if(tile >= *ntiles) return;
  int e = te[tile], base = tb[tile], send = ts[tile];
  int n0 = blockIdx.y*64;
  __shared__ short As[128*32];    // 8 KB
  __shared__ short Bs[64*32];     // 4 KB
  int tid = threadIdx.x;
  int srow0 = tid>>2, srow1 = 64 + (tid>>2), scol = (tid&3)*8;
  int r0g = base + srow0, r1g = base + srow1;
  int ar0 = (r0g < send) ? r0g : base;
  int ar1 = (r1g < send) ? r1g : base;
  const short* gA0 = (const short*)H + (size_t)ar0*FDIM + scol;
  const short* gA1 = (const short*)H + (size_t)ar1*FDIM + scol;
  const short* gB  = (const short*)w2T + ((size_t)e*DIM + n0 + srow0)*FDIM + scol;
  char* lA = (char*)As + tid*16;
  char* lB = (char*)Bs + tid*16;
  int wid = tid>>6, lane = tid&63, wr = wid>>1, wc = wid&1;
  int lrow = lane&15, lk = (lane>>4)<<3;
  f32x4 acc[4][2] = {};
  for(int k0=0; k0<FDIM; k0+=32){
    __syncthreads();
    g2l16(gA0 + k0, lA);
    g2l16(gA1 + k0, lA + 4096);
    g2l16(gB  + k0, lB);
    __syncthreads();
    bf16x8 af[4], bfr[2];
    #pragma unroll
    for(int m=0;m<4;m++) af[m]  = *(const bf16x8*)&As[(wr*64+m*16+lrow)*32 + lk];
    #pragma unroll
    for(int n=0;n<2;n++) bfr[n] = *(const bf16x8*)&Bs[(wc*32+n*16+lrow)*32 + lk];
    #pragma unroll
    for(int m=0;m<4;m++){
      #pragma unroll
      for(int n=0;n<2;n++)
        acc[m][n] = __builtin_amdgcn_mfma_f32_16x16x32_bf16(af[m], bfr[n], acc[m][n], 0,0,0);
    }
  }
  #pragma unroll
  for(int m=0;m<4;m++){
    #pragma unroll
    for(int j=0;j<4;j++){
      int r2 = base + wr*64 + m*16 + ((lane>>4)<<2) + j;
      if(r2 < send){
        #pragma unroll
        for(int n=0;n<2;n++){
          int col = n0 + wc*32 + n*16 + lrow;
          ((short*)O)[(size_t)r2*DIM + col] = f2bf(acc[m][n][j]);
        }
      }
    }
  }
}

// ---------------- combine: out[t] = w0*O[p0] + w1*O[p1] ----------------
__global__ __launch_bounds__(256) void k_combine(const bf16* __restrict__ O,
    const int* __restrict__ posmap, const float* __restrict__ tw,
    float* __restrict__ out){
  int lane = threadIdx.x & 63, wid = threadIdx.x >> 6;
  int t = blockIdx.x*4 + wid;
  int p0 = posmap[2*t], p1 = posmap[2*t+1];
  float w0 = tw[2*t], w1 = tw[2*t+1];
  s16x8 a = *(const s16x8*)((const short*)O + (size_t)p0*DIM + lane*8);
  s16x8 b = *(const s16x8*)((const short*)O + (size_t)p1*DIM + lane*8);
  f32x4 r0, r1;
  #pragma unroll
  for(int j=0;j<4;j++) r0[j] = w0*bf2f(a[j]) + w1*bf2f(b[j]);
  #pragma unroll
  for(int j=0;j<4;j++) r1[j] = w0*bf2f(a[4+j]) + w1*bf2f(b[4+j]);
  float* o = out + (size_t)t*DIM + lane*8;
  *(f32x4*)o = r0;
  *(f32x4*)(o+4) = r1;
}

extern "C" void kernel_launch(void* const* d_in, const int* in_sizes, int n_in,
                              void* d_out, int out_size, void* d_ws, size_t ws_size,
                              hipStream_t stream){
  const float* x  = (const float*)d_in[0];
  const float* gw = (const float*)d_in[1];
  const float* w1 = (const float*)d_in[2];
  const float* w2 = (const float*)d_in[3];
  const float* w3 = (const float*)d_in[4];
  float* out = (float*)d_out;
  char* ws = (char*)d_ws;

  int* cw = (int*)ws;
  int* counts = cw;                 // 8
  int* fill   = cw + 8;             // 8
  int* offsets= cw + 16;            // 8
  int* ntiles = cw + 24;            // 1 (+pad)
  int* te = cw + 32;                // 264
  int* tb = cw + 296;               // 264
  int* ts = cw + 560;               // 264
  int* tidx       = cw + 824;                 // PAIRS
  int* token_list = cw + 824 + PAIRS;         // PAIRS
  int* posmap     = cw + 824 + 2*PAIRS;       // PAIRS
  float* tw       = (float*)(cw + 824 + 3*PAIRS); // PAIRS

  const size_t MB = 1u<<20;
  bf16* xb  = (bf16*)(ws + 1*MB);           // 16 MiB
  bf16* w1T = (bf16*)(ws + 17*MB);          // 16 MiB
  bf16* w3T = (bf16*)(ws + 33*MB);          // 16 MiB
  bf16* w2T = (bf16*)(ws + 49*MB);          // 16 MiB
  bf16* Hbuf= (bf16*)(ws + 65*MB);          // PAIRS*FDIM*2 = 128 MiB
  bf16* Obuf= (bf16*)(ws + 17*MB);          // aliases w1T+w3T (32 MiB), dead by gemmB
  size_t needed = 65*MB + (size_t)PAIRS*FDIM*2u;
  if(ws_size < needed) return;

  hipMemsetAsync(d_ws, 0, 64, stream);      // counts + fill

  k_gate<<<N_TOK/8, 512, 0, stream>>>(x, gw, tidx, tw);
  k_count<<<PAIRS/1024, 256, 0, stream>>>(tidx, counts);
  k_route<<<1, 64, 0, stream>>>(counts, offsets, ntiles, te, tb, ts);
  k_scatter<<<PAIRS/256, 256, 0, stream>>>(tidx, offsets, fill, token_list, posmap);
  k_cast<<<(N_TOK*DIM/8)/256, 256, 0, stream>>>(x, xb);
  k_transpose<<<dim3(FDIM/32, DIM/32, NEXP), 256, 0, stream>>>(w1, w1T, DIM, FDIM);
  k_transpose<<<dim3(FDIM/32, DIM/32, NEXP), 256, 0, stream>>>(w3, w3T, DIM, FDIM);
  k_transpose<<<dim3(DIM/32, FDIM/32, NEXP), 256, 0, stream>>>(w2, w2T, FDIM, DIM);
  k_gemmA<<<dim3(MAX_TILES, FDIM/64), 256, 0, stream>>>(xb, w1T, w3T, ntiles, te, tb, ts, token_list, Hbuf);
  k_gemmB<<<dim3(MAX_TILES, DIM/64), 256, 0, stream>>>(Hbuf, w2T, ntiles, te, tb, ts, Obuf);
  k_combine<<<N_TOK/4, 256, 0, stream>>>(Obuf, posmap, tw, out);
}

// Round 9
// 511.629 us; speedup vs baseline: 4.0874x; 1.1528x over previous
//
#include <hip/hip_runtime.h>
#include <hip/hip_bf16.h>
#include <math.h>

#define N_TOK 16384
#define DIM   512
#define FDIM  2048
#define NEXP  8
#define TOPK  2
#define PAIRS (N_TOK*TOPK)             // 32768
#define MAX_TILES (PAIRS/128 + NEXP)   // 264

typedef __hip_bfloat16 bf16;
typedef __attribute__((ext_vector_type(8))) short bf16x8;
typedef __attribute__((ext_vector_type(4))) float f32x4;
typedef __attribute__((ext_vector_type(8))) short s16x8;

__device__ __forceinline__ short f2bf(float f){
  union { float f; unsigned u; } v; v.f = f;
  unsigned r = v.u + 0x7fffu + ((v.u >> 16) & 1u);
  return (short)(r >> 16);
}
__device__ __forceinline__ float bf2f(short s){
  union { unsigned u; float f; } v; v.u = ((unsigned)(unsigned short)s) << 16;
  return v.f;
}
// async global->LDS, 16B per lane. LDS dest = wave-uniform base + lane*16.
__device__ __forceinline__ void g2l16(const void* g, void* l){
  __builtin_amdgcn_global_load_lds(
      (const __attribute__((address_space(1))) unsigned int*)g,
      (__attribute__((address_space(3))) unsigned int*)l, 16, 0, 0);
}

// ---------------- gating: fp32 logits, top-2, softmax. NO global atomics ----------------
__global__ __launch_bounds__(512) void k_gate(const float* __restrict__ x,
    const float* __restrict__ gw, int* __restrict__ tidx, float* __restrict__ tw){
  __shared__ float gwT[NEXP][DIM];
  int tid = threadIdx.x;
  #pragma unroll
  for(int i=0;i<8;i++){
    int idx = tid + 512*i;
    gwT[idx&7][idx>>3] = gw[idx];
  }
  __syncthreads();
  int lane = tid & 63, wid = tid >> 6;
  int t = blockIdx.x*8 + wid;
  const float* xr = x + (size_t)t*DIM;
  float acc[NEXP];
  #pragma unroll
  for(int e=0;e<NEXP;e++) acc[e]=0.f;
  #pragma unroll
  for(int c=0;c<8;c++){
    float xv = xr[c*64 + lane];
    #pragma unroll
    for(int e=0;e<NEXP;e++) acc[e] += xv * gwT[e][c*64+lane];
  }
  #pragma unroll
  for(int off=32; off; off>>=1){
    #pragma unroll
    for(int e=0;e<NEXP;e++) acc[e] += __shfl_xor(acc[e], off);
  }
  if(lane==0){
    int e0=0; float v0=acc[0];
    #pragma unroll
    for(int e=1;e<NEXP;e++) if(acc[e]>v0){v0=acc[e]; e0=e;}
    int e1=-1; float v1=-1e30f;
    #pragma unroll
    for(int e=0;e<NEXP;e++) if(e!=e0 && acc[e]>v1){v1=acc[e]; e1=e;}
    float z = expf(v1-v0);
    float w0 = 1.f/(1.f+z);
    tidx[t*2]=e0; tidx[t*2+1]=e1;
    tw[t*2]=w0; tw[t*2+1]=1.f-w0;
  }
}

// ---------------- histogram: 8 global atomics per block ----------------
__global__ __launch_bounds__(256) void k_count(const int* __restrict__ tidx,
                                               int* __restrict__ counts){
  __shared__ int h[NEXP];
  if(threadIdx.x<NEXP) h[threadIdx.x]=0;
  __syncthreads();
  int i0 = blockIdx.x*1024 + threadIdx.x;
  #pragma unroll
  for(int k=0;k<4;k++) atomicAdd(&h[tidx[i0 + 256*k]], 1);
  __syncthreads();
  if(threadIdx.x<NEXP) atomicAdd(&counts[threadIdx.x], h[threadIdx.x]);
}

// ---------------- routing tables: dense offsets, ragged tiles ----------------
__global__ void k_route(const int* __restrict__ counts, int* __restrict__ offsets,
    int* __restrict__ ntiles, int* __restrict__ te, int* __restrict__ tb,
    int* __restrict__ ts){
  if(threadIdx.x==0){
    int off=0, nt=0;
    for(int e=0;e<NEXP;e++){
      offsets[e]=off;
      int c=counts[e];
      int tiles=(c+127)>>7;
      for(int i=0;i<tiles;i++){ te[nt]=e; tb[nt]=off+(i<<7); ts[nt]=off+c; nt++; }
      off += c;
    }
    *ntiles=nt;
  }
}

// ---------------- scatter: block-level reservation, dense positions ----------------
__global__ __launch_bounds__(256) void k_scatter(const int* __restrict__ tidx,
    const int* __restrict__ offsets, int* __restrict__ fill,
    int* __restrict__ token_list, int* __restrict__ posmap){
  __shared__ int lcnt[NEXP], lbase[NEXP];
  if(threadIdx.x<NEXP) lcnt[threadIdx.x]=0;
  __syncthreads();
  int i = blockIdx.x*256 + threadIdx.x;
  int e = tidx[i];
  int rank = atomicAdd(&lcnt[e], 1);
  __syncthreads();
  if(threadIdx.x<NEXP) lbase[threadIdx.x] = atomicAdd(&fill[threadIdx.x], lcnt[threadIdx.x]);
  __syncthreads();
  int pos = offsets[e] + lbase[e] + rank;
  token_list[pos] = i>>1;
  posmap[i] = pos;
}

// ---------------- fp32 -> bf16 cast (x) ----------------
__global__ __launch_bounds__(256) void k_cast(const float* __restrict__ x,
                                              bf16* __restrict__ xb){
  int i = blockIdx.x*256 + threadIdx.x;
  const float* p = x + (size_t)i*8;
  f32x4 a = *(const f32x4*)p;
  f32x4 b = *(const f32x4*)(p+4);
  s16x8 r;
  r[0]=f2bf(a[0]); r[1]=f2bf(a[1]); r[2]=f2bf(a[2]); r[3]=f2bf(a[3]);
  r[4]=f2bf(b[0]); r[5]=f2bf(b[1]); r[6]=f2bf(b[2]); r[7]=f2bf(b[3]);
  *(s16x8*)((short*)xb + (size_t)i*8) = r;
}

// ---------------- transpose+cast: src [R][C] f32 -> dst [C][R] bf16 ----------------
__global__ __launch_bounds__(256) void k_transpose(const float* __restrict__ src,
    bf16* __restrict__ dst, int R, int C){
  __shared__ float tile[32][33];
  const float* s = src + (size_t)blockIdx.z*R*C;
  short* d = (short*)dst + (size_t)blockIdx.z*R*C;
  int c0 = blockIdx.x*32, r0 = blockIdx.y*32;
  int tx = threadIdx.x & 31, ty = threadIdx.x >> 5;
  #pragma unroll
  for(int i=0;i<4;i++) tile[ty+8*i][tx] = s[(size_t)(r0+ty+8*i)*C + c0+tx];
  __syncthreads();
  #pragma unroll
  for(int i=0;i<4;i++) d[(size_t)(c0+ty+8*i)*R + r0+tx] = f2bf(tile[tx][ty+8*i]);
}

// ---------------- GEMM A: H[pos] = silu(X@w1) * (X@w3), gathered rows ----------------
// R8 lesson: occupancy (21->41%) did NOT move dur; limiter = serial stage/compute +
// 8-way LDS conflicts. This round: double-buffered staging (overlap loads under MFMA,
// 1 barrier/K-step) + swizzled LDS via pre-swizzled GLOBAL source (m173): LDS[r][c]
// holds global chunk c^((r>>1)&3) -> ds_read 2-way conflicts (free).
__global__ __launch_bounds__(256,3) void k_gemmA(const bf16* __restrict__ xb,
    const bf16* __restrict__ w1T, const bf16* __restrict__ w3T,
    const int* __restrict__ ntiles, const int* __restrict__ te,
    const int* __restrict__ tb, const int* __restrict__ ts,
    const int* __restrict__ token_list, bf16* __restrict__ H){
  int tile = blockIdx.x;
  if(tile >= *ntiles) return;
  int e = te[tile], base = tb[tile], send = ts[tile];
  int f0 = blockIdx.y*64;
  __shared__ short As[2*128*32];   // 16 KB (2 bufs)
  __shared__ short B1s[2*64*32];   // 8 KB
  __shared__ short B3s[2*64*32];   // 8 KB
  int tid = threadIdx.x;
  int srow0 = tid>>2, srow1 = 64 + (tid>>2);
  int sx = (tid>>3)&3;                       // ((srow>>1)&3), same for both halves
  int scol = ((tid&3) ^ sx)*8;               // pre-swizzled source column (shorts)
  int r0g = base + srow0, r1g = base + srow1;
  int tok0 = token_list[(r0g < send) ? r0g : base];
  int tok1 = token_list[(r1g < send) ? r1g : base];
  const short* gA0 = (const short*)xb + (size_t)tok0*DIM + scol;
  const short* gA1 = (const short*)xb + (size_t)tok1*DIM + scol;
  const short* gB1 = (const short*)w1T + ((size_t)e*FDIM + f0 + srow0)*DIM + scol;
  const short* gB3 = (const short*)w3T + ((size_t)e*FDIM + f0 + srow0)*DIM + scol;
  char* dA  = (char*)As  + tid*16;
  char* dB1 = (char*)B1s + tid*16;
  char* dB3 = (char*)B3s + tid*16;
  int wid = tid>>6, lane = tid&63;
  int wr = wid>>1, wc = wid&1;               // wave: rows wr*64, cols wc*32
  int lrow = lane&15, g = lane>>4;           // g = K-chunk index (16B chunks)
  f32x4 acc1[4][2] = {};
  f32x4 acc3[4][2] = {};
  // prologue: stage K-tile 0 into buf 0
  g2l16(gA0, dA);
  g2l16(gA1, dA + 4096);
  g2l16(gB1, dB1);
  g2l16(gB3, dB3);
  __syncthreads();
  int p = 0;
  for(int t=0; t<16; t++){
    if(t<15){
      int d1 = (t+1)*32;
      int ao = (p^1)*8192, bo = (p^1)*4096;
      g2l16(gA0 + d1, dA + ao);
      g2l16(gA1 + d1, dA + ao + 4096);
      g2l16(gB1 + d1, dB1 + bo);
      g2l16(gB3 + d1, dB3 + bo);
    }
    const short* Ab  = As  + p*4096;
    const short* B1b = B1s + p*2048;
    const short* B3b = B3s + p*2048;
    bf16x8 af[4], b1f[2], b3f[2];
    #pragma unroll
    for(int m=0;m<4;m++){
      int r = wr*64 + m*16 + lrow;
      af[m] = *(const bf16x8*)&Ab[r*32 + ((g ^ ((r>>1)&3))<<3)];
    }
    #pragma unroll
    for(int n=0;n<2;n++){
      int r = wc*32 + n*16 + lrow;
      int c = (g ^ ((r>>1)&3))<<3;
      b1f[n] = *(const bf16x8*)&B1b[r*32 + c];
      b3f[n] = *(const bf16x8*)&B3b[r*32 + c];
    }
    #pragma unroll
    for(int m=0;m<4;m++){
      #pragma unroll
      for(int n=0;n<2;n++){
        acc1[m][n] = __builtin_amdgcn_mfma_f32_16x16x32_bf16(af[m], b1f[n], acc1[m][n], 0,0,0);
        acc3[m][n] = __builtin_amdgcn_mfma_f32_16x16x32_bf16(af[m], b3f[n], acc3[m][n], 0,0,0);
      }
    }
    __syncthreads();
    p ^= 1;
  }
  #pragma unroll
  for(int m=0;m<4;m++){
    int r0 = base + wr*64 + m*16 + ((lane>>4)<<2);
    #pragma unroll
    for(int n=0;n<2;n++){
      int col = f0 + wc*32 + n*16 + lrow;
      #pragma unroll
      for(int j=0;j<4;j++){
        if(r0+j < send){
          float a = acc1[m][n][j];
          float h = a * (1.f/(1.f+__expf(-a))) * acc3[m][n][j];
          ((short*)H)[(size_t)(r0+j)*FDIM + col] = f2bf(h);
        }
      }
    }
  }
}

// ---------------- GEMM B: O[pos] = H[pos] @ w2  (no atomics) ----------------
// 128-col tiles (grid.y=4, undo R8 H-re-read doubling) + dbuf + swizzle; (256,3).
// regs: acc 64 + frags 32 + addr ~35 ~= 130 < 168 -> no spill.
__global__ __launch_bounds__(256,3) void k_gemmB(const bf16* __restrict__ H,
    const bf16* __restrict__ w2T, const int* __restrict__ ntiles,
    const int* __restrict__ te, const int* __restrict__ tb,
    const int* __restrict__ ts, bf16* __restrict__ O){
  int tile = blockIdx.x;
  if(tile >= *ntiles) return;
  int e = te[tile], base = tb[tile], send = ts[tile];
  int n0 = blockIdx.y*128;
  __shared__ short As[2*128*32];   // 16 KB
  __shared__ short Bs[2*128*32];   // 16 KB
  int tid = threadIdx.x;
  int srow0 = tid>>2, srow1 = 64 + (tid>>2);
  int sx = (tid>>3)&3;
  int scol = ((tid&3) ^ sx)*8;
  int r0g = base + srow0, r1g = base + srow1;
  int ar0 = (r0g < send) ? r0g : base;
  int ar1 = (r1g < send) ? r1g : base;
  const short* gA0 = (const short*)H + (size_t)ar0*FDIM + scol;
  const short* gA1 = (const short*)H + (size_t)ar1*FDIM + scol;
  const short* gB0 = (const short*)w2T + ((size_t)e*DIM + n0 + srow0)*FDIM + scol;
  const short* gB1 = (const short*)w2T + ((size_t)e*DIM + n0 + srow1)*FDIM + scol;
  char* dA = (char*)As + tid*16;
  char* dB = (char*)Bs + tid*16;
  int wid = tid>>6, lane = tid&63, wr = wid>>1, wc = wid&1;
  int lrow = lane&15, g = lane>>4;
  f32x4 acc[4][4] = {};
  g2l16(gA0, dA);
  g2l16(gA1, dA + 4096);
  g2l16(gB0, dB);
  g2l16(gB1, dB + 4096);
  __syncthreads();
  int p = 0;
  for(int t=0; t<64; t++){
    if(t<63){
      int d1 = (t+1)*32;
      int o = (p^1)*8192;
      g2l16(gA0 + d1, dA + o);
      g2l16(gA1 + d1, dA + o + 4096);
      g2l16(gB0 + d1, dB + o);
      g2l16(gB1 + d1, dB + o + 4096);
    }
    const short* Ab = As + p*4096;
    const short* Bb = Bs + p*4096;
    bf16x8 af[4], bfr[4];
    #pragma unroll
    for(int m=0;m<4;m++){
      int r = wr*64 + m*16 + lrow;
      af[m] = *(const bf16x8*)&Ab[r*32 + ((g ^ ((r>>1)&3))<<3)];
    }
    #pragma unroll
    for(int n=0;n<4;n++){
      int r = wc*64 + n*16 + lrow;
      bfr[n] = *(const bf16x8*)&Bb[r*32 + ((g ^ ((r>>1)&3))<<3)];
    }
    #pragma unroll
    for(int m=0;m<4;m++){
      #pragma unroll
      for(int n=0;n<4;n++)
        acc[m][n] = __builtin_amdgcn_mfma_f32_16x16x32_bf16(af[m], bfr[n], acc[m][n], 0,0,0);
    }
    __syncthreads();
    p ^= 1;
  }
  #pragma unroll
  for(int m=0;m<4;m++){
    #pragma unroll
    for(int j=0;j<4;j++){
      int r2 = base + wr*64 + m*16 + ((lane>>4)<<2) + j;
      if(r2 < send){
        #pragma unroll
        for(int n=0;n<4;n++){
          int col = n0 + wc*64 + n*16 + lrow;
          ((short*)O)[(size_t)r2*DIM + col] = f2bf(acc[m][n][j]);
        }
      }
    }
  }
}

// ---------------- combine: out[t] = w0*O[p0] + w1*O[p1] ----------------
__global__ __launch_bounds__(256) void k_combine(const bf16* __restrict__ O,
    const int* __restrict__ posmap, const float* __restrict__ tw,
    float* __restrict__ out){
  int lane = threadIdx.x & 63, wid = threadIdx.x >> 6;
  int t = blockIdx.x*4 + wid;
  int p0 = posmap[2*t], p1 = posmap[2*t+1];
  float w0 = tw[2*t], w1 = tw[2*t+1];
  s16x8 a = *(const s16x8*)((const short*)O + (size_t)p0*DIM + lane*8);
  s16x8 b = *(const s16x8*)((const short*)O + (size_t)p1*DIM + lane*8);
  f32x4 r0, r1;
  #pragma unroll
  for(int j=0;j<4;j++) r0[j] = w0*bf2f(a[j]) + w1*bf2f(b[j]);
  #pragma unroll
  for(int j=0;j<4;j++) r1[j] = w0*bf2f(a[4+j]) + w1*bf2f(b[4+j]);
  float* o = out + (size_t)t*DIM + lane*8;
  *(f32x4*)o = r0;
  *(f32x4*)(o+4) = r1;
}

extern "C" void kernel_launch(void* const* d_in, const int* in_sizes, int n_in,
                              void* d_out, int out_size, void* d_ws, size_t ws_size,
                              hipStream_t stream){
  const float* x  = (const float*)d_in[0];
  const float* gw = (const float*)d_in[1];
  const float* w1 = (const float*)d_in[2];
  const float* w2 = (const float*)d_in[3];
  const float* w3 = (const float*)d_in[4];
  float* out = (float*)d_out;
  char* ws = (char*)d_ws;

  int* cw = (int*)ws;
  int* counts = cw;                 // 8
  int* fill   = cw + 8;             // 8
  int* offsets= cw + 16;            // 8
  int* ntiles = cw + 24;            // 1 (+pad)
  int* te = cw + 32;                // 264
  int* tb = cw + 296;               // 264
  int* ts = cw + 560;               // 264
  int* tidx       = cw + 824;                 // PAIRS
  int* token_list = cw + 824 + PAIRS;         // PAIRS
  int* posmap     = cw + 824 + 2*PAIRS;       // PAIRS
  float* tw       = (float*)(cw + 824 + 3*PAIRS); // PAIRS

  const size_t MB = 1u<<20;
  bf16* xb  = (bf16*)(ws + 1*MB);           // 16 MiB
  bf16* w1T = (bf16*)(ws + 17*MB);          // 16 MiB
  bf16* w3T = (bf16*)(ws + 33*MB);          // 16 MiB
  bf16* w2T = (bf16*)(ws + 49*MB);          // 16 MiB
  bf16* Hbuf= (bf16*)(ws + 65*MB);          // PAIRS*FDIM*2 = 128 MiB
  bf16* Obuf= (bf16*)(ws + 17*MB);          // aliases w1T+w3T (32 MiB), dead by gemmB
  size_t needed = 65*MB + (size_t)PAIRS*FDIM*2u;
  if(ws_size < needed) return;

  hipMemsetAsync(d_ws, 0, 64, stream);      // counts + fill

  k_gate<<<N_TOK/8, 512, 0, stream>>>(x, gw, tidx, tw);
  k_count<<<PAIRS/1024, 256, 0, stream>>>(tidx, counts);
  k_route<<<1, 64, 0, stream>>>(counts, offsets, ntiles, te, tb, ts);
  k_scatter<<<PAIRS/256, 256, 0, stream>>>(tidx, offsets, fill, token_list, posmap);
  k_cast<<<(N_TOK*DIM/8)/256, 256, 0, stream>>>(x, xb);
  k_transpose<<<dim3(FDIM/32, DIM/32, NEXP), 256, 0, stream>>>(w1, w1T, DIM, FDIM);
  k_transpose<<<dim3(FDIM/32, DIM/32, NEXP), 256, 0, stream>>>(w3, w3T, DIM, FDIM);
  k_transpose<<<dim3(DIM/32, FDIM/32, NEXP), 256, 0, stream>>>(w2, w2T, FDIM, DIM);
  k_gemmA<<<dim3(MAX_TILES, FDIM/64), 256, 0, stream>>>(xb, w1T, w3T, ntiles, te, tb, ts, token_list, Hbuf);
  k_gemmB<<<dim3(MAX_TILES, DIM/128), 256, 0, stream>>>(Hbuf, w2T, ntiles, te, tb, ts, Obuf);
  k_combine<<<N_TOK/4, 256, 0, stream>>>(Obuf, posmap, tw, out);
}

// Round 12
// 502.637 us; speedup vs baseline: 4.1606x; 1.0179x over previous
//
#include <hip/hip_runtime.h>
#include <hip/hip_bf16.h>
#include <math.h>

#define N_TOK 16384
#define DIM   512
#define FDIM  2048
#define NEXP  8
#define TOPK  2
#define PAIRS (N_TOK*TOPK)             // 32768
#define MAX_TILES (PAIRS/128 + NEXP)   // 264 = 8*33

typedef __hip_bfloat16 bf16;
typedef __attribute__((ext_vector_type(8))) short bf16x8;
typedef __attribute__((ext_vector_type(4))) float f32x4;
typedef __attribute__((ext_vector_type(8))) short s16x8;

#define WAIT_VM4   asm volatile("s_waitcnt vmcnt(4)" ::: "memory")
#define WAIT_VM0   asm volatile("s_waitcnt vmcnt(0)" ::: "memory")
#define WAIT_LGKM0 asm volatile("s_waitcnt lgkmcnt(0)" ::: "memory")
#define SFENCE     __builtin_amdgcn_sched_barrier(0)
#define BAR        __builtin_amdgcn_s_barrier()

__device__ __forceinline__ short f2bf(float f){
  union { float f; unsigned u; } v; v.f = f;
  unsigned r = v.u + 0x7fffu + ((v.u >> 16) & 1u);
  return (short)(r >> 16);
}
__device__ __forceinline__ float bf2f(short s){
  union { unsigned u; float f; } v; v.u = ((unsigned)(unsigned short)s) << 16;
  return v.f;
}
// async global->LDS, 16B per lane. LDS dest = wave-uniform base + lane*16.
__device__ __forceinline__ void g2l16(const void* g, void* l){
  __builtin_amdgcn_global_load_lds(
      (const __attribute__((address_space(1))) unsigned int*)g,
      (__attribute__((address_space(3))) unsigned int*)l, 16, 0, 0);
}

// ---------------- gating: fp32 logits, top-2, softmax. NO global atomics ----------------
__global__ __launch_bounds__(512) void k_gate(const float* __restrict__ x,
    const float* __restrict__ gw, int* __restrict__ tidx, float* __restrict__ tw){
  __shared__ float gwT[NEXP][DIM];
  int tid = threadIdx.x;
  #pragma unroll
  for(int i=0;i<8;i++){
    int idx = tid + 512*i;
    gwT[idx&7][idx>>3] = gw[idx];
  }
  __syncthreads();
  int lane = tid & 63, wid = tid >> 6;
  int t = blockIdx.x*8 + wid;
  const float* xr = x + (size_t)t*DIM;
  float acc[NEXP];
  #pragma unroll
  for(int e=0;e<NEXP;e++) acc[e]=0.f;
  #pragma unroll
  for(int c=0;c<8;c++){
    float xv = xr[c*64 + lane];
    #pragma unroll
    for(int e=0;e<NEXP;e++) acc[e] += xv * gwT[e][c*64+lane];
  }
  #pragma unroll
  for(int off=32; off; off>>=1){
    #pragma unroll
    for(int e=0;e<NEXP;e++) acc[e] += __shfl_xor(acc[e], off);
  }
  if(lane==0){
    int e0=0; float v0=acc[0];
    #pragma unroll
    for(int e=1;e<NEXP;e++) if(acc[e]>v0){v0=acc[e]; e0=e;}
    int e1=-1; float v1=-1e30f;
    #pragma unroll
    for(int e=0;e<NEXP;e++) if(e!=e0 && acc[e]>v1){v1=acc[e]; e1=e;}
    float z = expf(v1-v0);
    float w0 = 1.f/(1.f+z);
    tidx[t*2]=e0; tidx[t*2+1]=e1;
    tw[t*2]=w0; tw[t*2+1]=1.f-w0;
  }
}

// ---------------- histogram: 8 global atomics per block ----------------
__global__ __launch_bounds__(256) void k_count(const int* __restrict__ tidx,
                                               int* __restrict__ counts){
  __shared__ int h[NEXP];
  if(threadIdx.x<NEXP) h[threadIdx.x]=0;
  __syncthreads();
  int i0 = blockIdx.x*1024 + threadIdx.x;
  #pragma unroll
  for(int k=0;k<4;k++) atomicAdd(&h[tidx[i0 + 256*k]], 1);
  __syncthreads();
  if(threadIdx.x<NEXP) atomicAdd(&counts[threadIdx.x], h[threadIdx.x]);
}

// ---------------- routing tables: dense offsets, ragged tiles ----------------
__global__ void k_route(const int* __restrict__ counts, int* __restrict__ offsets,
    int* __restrict__ ntiles, int* __restrict__ te, int* __restrict__ tb,
    int* __restrict__ ts){
  if(threadIdx.x==0){
    int off=0, nt=0;
    for(int e=0;e<NEXP;e++){
      offsets[e]=off;
      int c=counts[e];
      int tiles=(c+127)>>7;
      for(int i=0;i<tiles;i++){ te[nt]=e; tb[nt]=off+(i<<7); ts[nt]=off+c; nt++; }
      off += c;
    }
    *ntiles=nt;
  }
}

// ---------------- scatter: block-level reservation, dense positions ----------------
__global__ __launch_bounds__(256) void k_scatter(const int* __restrict__ tidx,
    const int* __restrict__ offsets, int* __restrict__ fill,
    int* __restrict__ token_list, int* __restrict__ posmap){
  __shared__ int lcnt[NEXP], lbase[NEXP];
  if(threadIdx.x<NEXP) lcnt[threadIdx.x]=0;
  __syncthreads();
  int i = blockIdx.x*256 + threadIdx.x;
  int e = tidx[i];
  int rank = atomicAdd(&lcnt[e], 1);
  __syncthreads();
  if(threadIdx.x<NEXP) lbase[threadIdx.x] = atomicAdd(&fill[threadIdx.x], lcnt[threadIdx.x]);
  __syncthreads();
  int pos = offsets[e] + lbase[e] + rank;
  token_list[pos] = i>>1;
  posmap[i] = pos;
}

// ---------------- fp32 -> bf16 cast (x) ----------------
__global__ __launch_bounds__(256) void k_cast(const float* __restrict__ x,
                                              bf16* __restrict__ xb){
  int i = blockIdx.x*256 + threadIdx.x;
  const float* p = x + (size_t)i*8;
  f32x4 a = *(const f32x4*)p;
  f32x4 b = *(const f32x4*)(p+4);
  s16x8 r;
  r[0]=f2bf(a[0]); r[1]=f2bf(a[1]); r[2]=f2bf(a[2]); r[3]=f2bf(a[3]);
  r[4]=f2bf(b[0]); r[5]=f2bf(b[1]); r[6]=f2bf(b[2]); r[7]=f2bf(b[3]);
  *(s16x8*)((short*)xb + (size_t)i*8) = r;
}

// ---------------- transpose+cast: src [R][C] f32 -> dst [C][R] bf16 ----------------
__global__ __launch_bounds__(256) void k_transpose(const float* __restrict__ src,
    bf16* __restrict__ dst, int R, int C){
  __shared__ float tile[32][33];
  const float* s = src + (size_t)blockIdx.z*R*C;
  short* d = (short*)dst + (size_t)blockIdx.z*R*C;
  int c0 = blockIdx.x*32, r0 = blockIdx.y*32;
  int tx = threadIdx.x & 31, ty = threadIdx.x >> 5;
  #pragma unroll
  for(int i=0;i<4;i++) tile[ty+8*i][tx] = s[(size_t)(r0+ty+8*i)*C + c0+tx];
  __syncthreads();
  #pragma unroll
  for(int i=0;i<4;i++) d[(size_t)(c0+ty+8*i)*R + r0+tx] = f2bf(tile[tx][ty+8*i]);
}

// ---------------- GEMM A: H[pos] = silu(X@w1) * (X@w3), gathered rows ----------------
// Counted-vmcnt pipeline (T4, m218): raw s_barrier + vmcnt(4), 3-deep; loads stay in
// flight ACROSS barriers. Swizzle (R9, conflicts=0) retained.
// NEW (R11): XCD tile-chunk swizzle. XCD = linear-bid % 8 and gridDim.x=264 (%8==0),
// so default gives each XCD tiles interleaved across ALL experts -> every XCD streams
// all 32MB of B -> L2 thrash (FETCH 320MB vs 48MB unique). Remap tile=(bx&7)*33+bx>>3:
// each XCD owns a contiguous 33-tile chunk (~1 expert), B/XCD ~4MB = L2-resident.
#define GA_STAGE(t, pb) do{ int _d=(t)*32; int _ao=(pb)*8192, _bo=(pb)*4096; \
  g2l16(gA0+_d, dA+_ao); g2l16(gA1+_d, dA+_ao+4096); \
  g2l16(gB1+_d, dB1+_bo); g2l16(gB3+_d, dB3+_bo); }while(0)
#define GA_READ(pb) do{ const short* Ab=As+(pb)*4096; const short* B1b=B1s+(pb)*2048; const short* B3b=B3s+(pb)*2048; \
  _Pragma("unroll") for(int m=0;m<4;m++){ int r=wr*64+m*16+lrow; af[m]=*(const bf16x8*)&Ab[r*32+((g^((r>>1)&3))<<3)]; } \
  _Pragma("unroll") for(int n=0;n<2;n++){ int r=wc*32+n*16+lrow; int c=(g^((r>>1)&3))<<3; \
    b1f[n]=*(const bf16x8*)&B1b[r*32+c]; b3f[n]=*(const bf16x8*)&B3b[r*32+c]; } }while(0)
#define GA_MMA() do{ _Pragma("unroll") for(int m=0;m<4;m++){ _Pragma("unroll") for(int n=0;n<2;n++){ \
  acc1[m][n]=__builtin_amdgcn_mfma_f32_16x16x32_bf16(af[m],b1f[n],acc1[m][n],0,0,0); \
  acc3[m][n]=__builtin_amdgcn_mfma_f32_16x16x32_bf16(af[m],b3f[n],acc3[m][n],0,0,0);}} }while(0)
__global__ __launch_bounds__(256,3) void k_gemmA(const bf16* __restrict__ xb,
    const bf16* __restrict__ w1T, const bf16* __restrict__ w3T,
    const int* __restrict__ ntiles, const int* __restrict__ te,
    const int* __restrict__ tb, const int* __restrict__ ts,
    const int* __restrict__ token_list, bf16* __restrict__ H){
  int bx = blockIdx.x;
  int tile = (bx&7)*33 + (bx>>3);          // bijective: 264 = 8*33
  if(tile >= *ntiles) return;
  int e = te[tile], base = tb[tile], send = ts[tile];
  int f0 = blockIdx.y*64;
  __shared__ short As[2*128*32];   // 16 KB (2 bufs)
  __shared__ short B1s[2*64*32];   // 8 KB
  __shared__ short B3s[2*64*32];   // 8 KB
  int tid = threadIdx.x;
  int srow0 = tid>>2, srow1 = 64 + (tid>>2);
  int sx = (tid>>3)&3;                       // ((srow>>1)&3)
  int scol = ((tid&3) ^ sx)*8;               // pre-swizzled source column (shorts)
  int r0g = base + srow0, r1g = base + srow1;
  int tok0 = token_list[(r0g < send) ? r0g : base];
  int tok1 = token_list[(r1g < send) ? r1g : base];
  const short* gA0 = (const short*)xb + (size_t)tok0*DIM + scol;
  const short* gA1 = (const short*)xb + (size_t)tok1*DIM + scol;
  const short* gB1 = (const short*)w1T + ((size_t)e*FDIM + f0 + srow0)*DIM + scol;
  const short* gB3 = (const short*)w3T + ((size_t)e*FDIM + f0 + srow0)*DIM + scol;
  char* dA  = (char*)As  + tid*16;
  char* dB1 = (char*)B1s + tid*16;
  char* dB3 = (char*)B3s + tid*16;
  int wid = tid>>6, lane = tid&63;
  int wr = wid>>1, wc = wid&1;               // wave: rows wr*64, cols wc*32
  int lrow = lane&15, g = lane>>4;
  f32x4 acc1[4][2] = {};
  f32x4 acc3[4][2] = {};
  GA_STAGE(0,0);
  GA_STAGE(1,1);
  WAIT_VM4; SFENCE; BAR;                     // tile0 ready; tile1 stays in flight
  int p = 0;
  #pragma unroll 1
  for(int t=0; t<14; ++t){
    bf16x8 af[4], b1f[2], b3f[2];
    GA_READ(p);
    WAIT_LGKM0; SFENCE;
    BAR;                                     // all waves done reading buf[p]
    GA_STAGE(t+2, p);                        // overwrite read-out buffer
    GA_MMA();                                // compute while 8 loads fly
    WAIT_VM4; SFENCE;                        // tile t+1 landed (t+2 still flying)
    BAR;
    p ^= 1;
  }
  { // t=14: no stage left
    bf16x8 af[4], b1f[2], b3f[2];
    GA_READ(p);
    GA_MMA();
    WAIT_VM0; SFENCE;                        // tile15 landed
    BAR;
    p ^= 1;
  }
  { // t=15
    bf16x8 af[4], b1f[2], b3f[2];
    GA_READ(p);
    GA_MMA();
  }
  #pragma unroll
  for(int m=0;m<4;m++){
    int r0 = base + wr*64 + m*16 + ((lane>>4)<<2);
    #pragma unroll
    for(int n=0;n<2;n++){
      int col = f0 + wc*32 + n*16 + lrow;
      #pragma unroll
      for(int j=0;j<4;j++){
        if(r0+j < send){
          float a = acc1[m][n][j];
          float h = a * (1.f/(1.f+__expf(-a))) * acc3[m][n][j];
          ((short*)H)[(size_t)(r0+j)*FDIM + col] = f2bf(h);
        }
      }
    }
  }
}

// ---------------- GEMM B: O[pos] = H[pos] @ w2  (no atomics) ----------------
#define GB_STAGE(t, pb) do{ int _d=(t)*32; int _o=(pb)*8192; \
  g2l16(gA0+_d, dA+_o); g2l16(gA1+_d, dA+_o+4096); \
  g2l16(gB0+_d, dB+_o); g2l16(gB1+_d, dB+_o+4096); }while(0)
#define GB_READ(pb) do{ const short* Ab=As+(pb)*4096; const short* Bb=Bs+(pb)*4096; \
  _Pragma("unroll") for(int m=0;m<4;m++){ int r=wr*64+m*16+lrow; af[m]=*(const bf16x8*)&Ab[r*32+((g^((r>>1)&3))<<3)]; } \
  _Pragma("unroll") for(int n=0;n<4;n++){ int r=wc*64+n*16+lrow; bfr[n]=*(const bf16x8*)&Bb[r*32+((g^((r>>1)&3))<<3)]; } }while(0)
#define GB_MMA() do{ _Pragma("unroll") for(int m=0;m<4;m++){ _Pragma("unroll") for(int n=0;n<4;n++) \
  acc[m][n]=__builtin_amdgcn_mfma_f32_16x16x32_bf16(af[m],bfr[n],acc[m][n],0,0,0); } }while(0)
__global__ __launch_bounds__(256,3) void k_gemmB(const bf16* __restrict__ H,
    const bf16* __restrict__ w2T, const int* __restrict__ ntiles,
    const int* __restrict__ te, const int* __restrict__ tb,
    const int* __restrict__ ts, bf16* __restrict__ O){
  int bx = blockIdx.x;
  int tile = (bx&7)*33 + (bx>>3);          // XCD chunk swizzle (see gemmA)
  if(tile >= *ntiles) return;
  int e = te[tile], base = tb[tile], send = ts[tile];
  int n0 = blockIdx.y*128;
  __shared__ short As[2*128*32];   // 16 KB
  __shared__ short Bs[2*128*32];   // 16 KB
  int tid = threadIdx.x;
  int srow0 = tid>>2, srow1 = 64 + (tid>>2);
  int sx = (tid>>3)&3;
  int scol = ((tid&3) ^ sx)*8;
  int r0g = base + srow0, r1g = base + srow1;
  int ar0 = (r0g < send) ? r0g : base;
  int ar1 = (r1g < send) ? r1g : base;
  const short* gA0 = (const short*)H + (size_t)ar0*FDIM + scol;
  const short* gA1 = (const short*)H + (size_t)ar1*FDIM + scol;
  const short* gB0 = (const short*)w2T + ((size_t)e*DIM + n0 + srow0)*FDIM + scol;
  const short* gB1 = (const short*)w2T + ((size_t)e*DIM + n0 + srow1)*FDIM + scol;
  char* dA = (char*)As + tid*16;
  char* dB = (char*)Bs + tid*16;
  int wid = tid>>6, lane = tid&63, wr = wid>>1, wc = wid&1;
  int lrow = lane&15, g = lane>>4;
  f32x4 acc[4][4] = {};
  GB_STAGE(0,0);
  GB_STAGE(1,1);
  WAIT_VM4; SFENCE; BAR;
  int p = 0;
  #pragma unroll 1
  for(int t=0; t<62; ++t){
    bf16x8 af[4], bfr[4];
    GB_READ(p);
    WAIT_LGKM0; SFENCE;
    BAR;
    GB_STAGE(t+2, p);
    GB_MMA();
    WAIT_VM4; SFENCE;
    BAR;
    p ^= 1;
  }
  { // t=62
    bf16x8 af[4], bfr[4];
    GB_READ(p);
    GB_MMA();
    WAIT_VM0; SFENCE;
    BAR;
    p ^= 1;
  }
  { // t=63
    bf16x8 af[4], bfr[4];
    GB_READ(p);
    GB_MMA();
  }
  #pragma unroll
  for(int m=0;m<4;m++){
    #pragma unroll
    for(int j=0;j<4;j++){
      int r2 = base + wr*64 + m*16 + ((lane>>4)<<2) + j;
      if(r2 < send){
        #pragma unroll
        for(int n=0;n<4;n++){
          int col = n0 + wc*64 + n*16 + lrow;
          ((short*)O)[(size_t)r2*DIM + col] = f2bf(acc[m][n][j]);
        }
      }
    }
  }
}

// ---------------- combine: out[t] = w0*O[p0] + w1*O[p1] ----------------
__global__ __launch_bounds__(256) void k_combine(const bf16* __restrict__ O,
    const int* __restrict__ posmap, const float* __restrict__ tw,
    float* __restrict__ out){
  int lane = threadIdx.x & 63, wid = threadIdx.x >> 6;
  int t = blockIdx.x*4 + wid;
  int p0 = posmap[2*t], p1 = posmap[2*t+1];
  float w0 = tw[2*t], w1 = tw[2*t+1];
  s16x8 a = *(const s16x8*)((const short*)O + (size_t)p0*DIM + lane*8);
  s16x8 b = *(const s16x8*)((const short*)O + (size_t)p1*DIM + lane*8);
  f32x4 r0, r1;
  #pragma unroll
  for(int j=0;j<4;j++) r0[j] = w0*bf2f(a[j]) + w1*bf2f(b[j]);
  #pragma unroll
  for(int j=0;j<4;j++) r1[j] = w0*bf2f(a[4+j]) + w1*bf2f(b[4+j]);
  float* o = out + (size_t)t*DIM + lane*8;
  *(f32x4*)o = r0;
  *(f32x4*)(o+4) = r1;
}

extern "C" void kernel_launch(void* const* d_in, const int* in_sizes, int n_in,
                              void* d_out, int out_size, void* d_ws, size_t ws_size,
                              hipStream_t stream){
  const float* x  = (const float*)d_in[0];
  const float* gw = (const float*)d_in[1];
  const float* w1 = (const float*)d_in[2];
  const float* w2 = (const float*)d_in[3];
  const float* w3 = (const float*)d_in[4];
  float* out = (float*)d_out;
  char* ws = (char*)d_ws;

  int* cw = (int*)ws;
  int* counts = cw;                 // 8
  int* fill   = cw + 8;             // 8
  int* offsets= cw + 16;            // 8
  int* ntiles = cw + 24;            // 1 (+pad)
  int* te = cw + 32;                // 264
  int* tb = cw + 296;               // 264
  int* ts = cw + 560;               // 264
  int* tidx       = cw + 824;                 // PAIRS
  int* token_list = cw + 824 + PAIRS;         // PAIRS
  int* posmap     = cw + 824 + 2*PAIRS;       // PAIRS
  float* tw       = (float*)(cw + 824 + 3*PAIRS); // PAIRS

  const size_t MB = 1u<<20;
  bf16* xb  = (bf16*)(ws + 1*MB);           // 16 MiB
  bf16* w1T = (bf16*)(ws + 17*MB);          // 16 MiB
  bf16* w3T = (bf16*)(ws + 33*MB);          // 16 MiB
  bf16* w2T = (bf16*)(ws + 49*MB);          // 16 MiB
  bf16* Hbuf= (bf16*)(ws + 65*MB);          // PAIRS*FDIM*2 = 128 MiB
  bf16* Obuf= (bf16*)(ws + 17*MB);          // aliases w1T+w3T (32 MiB), dead by gemmB
  size_t needed = 65*MB + (size_t)PAIRS*FDIM*2u;
  if(ws_size < needed) return;

  hipMemsetAsync(d_ws, 0, 64, stream);      // counts + fill

  k_gate<<<N_TOK/8, 512, 0, stream>>>(x, gw, tidx, tw);
  k_count<<<PAIRS/1024, 256, 0, stream>>>(tidx, counts);
  k_route<<<1, 64, 0, stream>>>(counts, offsets, ntiles, te, tb, ts);
  k_scatter<<<PAIRS/256, 256, 0, stream>>>(tidx, offsets, fill, token_list, posmap);
  k_cast<<<(N_TOK*DIM/8)/256, 256, 0, stream>>>(x, xb);
  k_transpose<<<dim3(FDIM/32, DIM/32, NEXP), 256, 0, stream>>>(w1, w1T, DIM, FDIM);
  k_transpose<<<dim3(FDIM/32, DIM/32, NEXP), 256, 0, stream>>>(w3, w3T, DIM, FDIM);
  k_transpose<<<dim3(DIM/32, FDIM/32, NEXP), 256, 0, stream>>>(w2, w2T, FDIM, DIM);
  k_gemmA<<<dim3(MAX_TILES, FDIM/64), 256, 0, stream>>>(xb, w1T, w3T, ntiles, te, tb, ts, token_list, Hbuf);
  k_gemmB<<<dim3(MAX_TILES, DIM/128), 256, 0, stream>>>(Hbuf, w2T, ntiles, te, tb, ts, Obuf);
  k_combine<<<N_TOK/4, 256, 0, stream>>>(Obuf, posmap, tw, out);
}